// Round 1
// baseline (906.225 us; speedup 1.0000x reference)
//
#include <hip/hip_runtime.h>

#define N_VOX  262144
#define BATCH  4
#define NBOX   32
#define C3D_   64
#define C2D_   256
#define MIDC   128
#define OUTC   64
#define IH     96
#define IW     312
#define IHW    (IH*IW)          // 29952
#define EPSF   1e-5f

// ---------------------------------------------------------------------------
// Kernel A: it[b][p][o] = relu(BN(sum_c w_it[o][c]*img[b][c][p]))
// 256 threads, 64 pixels x 128 outputs per block, K staged in chunks of 64.
// ---------------------------------------------------------------------------
__global__ __launch_bounds__(256) void img_transform(
    const float* __restrict__ img,    // [B][256][H*W]
    const float* __restrict__ w_it,   // [128][256]
    const float* __restrict__ b_it, const float* __restrict__ g_it,
    const float* __restrict__ be_it, const float* __restrict__ m_it,
    const float* __restrict__ v_it,
    float* __restrict__ it_out)       // [B][H*W][128]
{
    __shared__ __align__(16) float xs[64*64];   // [k][p]
    __shared__ float wt[128*65];                // [o][k], pitch 65 (conflict-free)

    const int p0  = blockIdx.x * 64;
    const int b   = blockIdx.y;
    const int tid = threadIdx.x;
    const int pg  = tid >> 4;     // 0..15 -> pixels pg*4..pg*4+3
    const int og  = tid & 15;     // 0..15 -> outputs og+16j, j=0..7

    float acc[4][8];
    #pragma unroll
    for (int i = 0; i < 4; ++i)
        #pragma unroll
        for (int j = 0; j < 8; ++j) acc[i][j] = 0.f;

    for (int kc = 0; kc < 4; ++kc) {
        // stage activations: 64 channels x 64 pixels
        #pragma unroll
        for (int jj = 0; jj < 16; ++jj) {
            int i = tid + 256*jj;
            int c = i >> 6, p = i & 63;
            xs[c*64 + p] = img[(b*C2D_ + kc*64 + c)*IHW + p0 + p];
        }
        // stage weights: 128 outs x 64 channels
        #pragma unroll
        for (int jj = 0; jj < 32; ++jj) {
            int i = tid + 256*jj;
            int o = i >> 6, k = i & 63;
            wt[o*65 + k] = w_it[o*256 + kc*64 + k];
        }
        __syncthreads();
        #pragma unroll 4
        for (int k = 0; k < 64; ++k) {
            float4 xv = *(const float4*)&xs[k*64 + pg*4];
            float wv[8];
            #pragma unroll
            for (int j = 0; j < 8; ++j) wv[j] = wt[(og + 16*j)*65 + k];
            const float xi0 = xv.x, xi1 = xv.y, xi2 = xv.z, xi3 = xv.w;
            #pragma unroll
            for (int j = 0; j < 8; ++j) {
                acc[0][j] = fmaf(xi0, wv[j], acc[0][j]);
                acc[1][j] = fmaf(xi1, wv[j], acc[1][j]);
                acc[2][j] = fmaf(xi2, wv[j], acc[2][j]);
                acc[3][j] = fmaf(xi3, wv[j], acc[3][j]);
            }
        }
        __syncthreads();
    }

    #pragma unroll
    for (int j = 0; j < 8; ++j) {
        int o = og + 16*j;
        float a  = g_it[o] * rsqrtf(v_it[o] + EPSF);
        float bb = (b_it[o] - m_it[o]) * a + be_it[o];
        #pragma unroll
        for (int i = 0; i < 4; ++i) {
            float val = fmaxf(acc[i][j]*a + bb, 0.f);
            it_out[(b*IHW + p0 + pg*4 + i)*MIDC + o] = val;
        }
    }
}

// ---------------------------------------------------------------------------
// Kernel B: per 32-voxel tile: meta (corners/weights/w3d), vt GEMM,
// bilinear gather, final 256->64 GEMM, all fused through LDS.
// ---------------------------------------------------------------------------
__global__ __launch_bounds__(256) void voxel_fuse(
    const float* __restrict__ vf,     // [N][64]
    const int*   __restrict__ coords, // [N][4] (b,z,y,x)
    const float* __restrict__ gtb,    // [B][32][7]
    const int*   __restrict__ gtc,    // [B][32]
    const float* __restrict__ w_vt,   // [128][64]
    const float* __restrict__ b_vt, const float* __restrict__ g_vt,
    const float* __restrict__ be_vt, const float* __restrict__ m_vt,
    const float* __restrict__ v_vt,
    const float* __restrict__ it_in,  // [B][H*W][128]
    const float* __restrict__ w_f,    // [64][256]
    const float* __restrict__ b_f, const float* __restrict__ g_f,
    const float* __restrict__ be_f, const float* __restrict__ m_f,
    const float* __restrict__ v_f,
    float* __restrict__ out)          // [N][64]
{
    __shared__ __align__(16) float s_fused[32*260];  // [v][ch], pitch 260
    __shared__ float s_vfs[64*33];                   // [k][v], pitch 33
    __shared__ float s_wvt[128*65];                  // [o][k], pitch 65
    __shared__ int   s_addr[4][32];
    __shared__ float s_wgt[4][32];
    __shared__ float s_w3d[32];

    const int tid = threadIdx.x;
    const int v0  = blockIdx.x * 32;

    // stage voxel features: 32 voxels x 64 k  ([k][v] transposed, pad 33)
    #pragma unroll
    for (int jj = 0; jj < 8; ++jj) {
        int i = tid + 256*jj;
        int v = i >> 6, k = i & 63;
        s_vfs[k*33 + v] = vf[(v0 + v)*C3D_ + k];
    }
    // stage w_vt: 128 x 64
    #pragma unroll
    for (int jj = 0; jj < 32; ++jj) {
        int i = tid + 256*jj;
        int o = i >> 6, k = i & 63;
        s_wvt[o*65 + k] = w_vt[o*C3D_ + k];
    }

    if (tid < 32) {
        const int v = tid;
        const int4 cc = ((const int4*)coords)[v0 + v];
        const int b = cc.x;
        const float crx = cc.w * 0.05f + 0.0f;
        const float cry = cc.z * 0.05f - 40.0f;
        const float crz = cc.y * 0.1f  - 3.0f;
        const float px = (crx + 0.025f) * 10.f + 156.f;   // + W/2
        const float py = (cry + 0.025f) * 10.f + 48.f;    // + H/2
        const float nx = fminf(fmaxf(px / 312.f * 2.f - 1.f, -1.f), 1.f);
        const float ny = fminf(fmaxf(py / 96.f  * 2.f - 1.f, -1.f), 1.f);
        const float fx = ((nx + 1.f) * 312.f - 1.f) * 0.5f;
        const float fy = ((ny + 1.f) * 96.f  - 1.f) * 0.5f;
        const float x0f = floorf(fx), y0f = floorf(fy);
        const float wx1 = fx - x0f, wy1 = fy - y0f;
        const int x0 = (int)x0f, y0 = (int)y0f;
        #pragma unroll
        for (int c = 0; c < 4; ++c) {
            int xi = x0 + (c & 1), yi = y0 + (c >> 1);
            bool valid = (xi >= 0) && (xi < IW) && (yi >= 0) && (yi < IH);
            int xc = min(max(xi, 0), IW - 1);
            int yc = min(max(yi, 0), IH - 1);
            s_addr[c][v] = ((b*IH + yc)*IW + xc) * MIDC;
            float wx = (c & 1) ? wx1 : 1.f - wx1;
            float wy = (c >> 1) ? wy1 : 1.f - wy1;
            s_wgt[c][v] = valid ? wx * wy : 0.f;
        }
        // box membership: last (largest m) inside box wins
        const float* gb = gtb + b*NBOX*7;
        bool any = false; int last = 0;
        for (int m = 0; m < NBOX; ++m) {
            float dx = gb[m*7+3];
            bool in = (fabsf(crx - gb[m*7+0]) < dx * 0.5f) &&
                      (fabsf(cry - gb[m*7+1]) < gb[m*7+4] * 0.5f) &&
                      (fabsf(crz - gb[m*7+2]) < gb[m*7+5] * 0.5f) &&
                      (dx > 0.f);
            if (in) { any = true; last = m; }
        }
        float w3 = 0.8f;
        if (any) {
            int cls = gtc[b*NBOX + last];
            w3 = (cls == 0) ? 0.85f : ((cls == 1) ? 0.95f : 0.6f);
        }
        s_w3d[v] = w3;
    }
    __syncthreads();

    // phase 1a: vt = relu(BN(vf @ w_vt^T)) * w3d  -> fused[v][0..127]
    {
        const int vg = tid >> 5;   // 0..7  -> voxels vg*4..vg*4+3
        const int og = tid & 31;   // 0..31 -> outs og+32j, j=0..3
        float acc[4][4];
        #pragma unroll
        for (int i = 0; i < 4; ++i)
            #pragma unroll
            for (int j = 0; j < 4; ++j) acc[i][j] = 0.f;
        #pragma unroll 4
        for (int k = 0; k < 64; ++k) {
            float fv[4], wv[4];
            #pragma unroll
            for (int i = 0; i < 4; ++i) fv[i] = s_vfs[k*33 + vg*4 + i];
            #pragma unroll
            for (int j = 0; j < 4; ++j) wv[j] = s_wvt[(og + 32*j)*65 + k];
            #pragma unroll
            for (int i = 0; i < 4; ++i)
                #pragma unroll
                for (int j = 0; j < 4; ++j)
                    acc[i][j] = fmaf(fv[i], wv[j], acc[i][j]);
        }
        #pragma unroll
        for (int j = 0; j < 4; ++j) {
            int o = og + 32*j;
            float a  = g_vt[o] * rsqrtf(v_vt[o] + EPSF);
            float bb = (b_vt[o] - m_vt[o]) * a + be_vt[o];
            #pragma unroll
            for (int i = 0; i < 4; ++i) {
                int v = vg*4 + i;
                s_fused[v*260 + o] = fmaxf(acc[i][j]*a + bb, 0.f) * s_w3d[v];
            }
        }
    }

    // phase 1b: sampled * (1 - w3d) -> fused[v][128..255]
    {
        const int o  = tid & 127;
        const int vh = tid >> 7;   // 0..1
        #pragma unroll 2
        for (int vi = 0; vi < 16; ++vi) {
            int v = vh*16 + vi;
            float s = 0.f;
            #pragma unroll
            for (int c = 0; c < 4; ++c)
                s = fmaf(s_wgt[c][v], it_in[s_addr[c][v] + o], s);
            s_fused[v*260 + 128 + o] = s * (1.f - s_w3d[v]);
        }
    }
    __syncthreads();

    // phase 2: out = relu(BN(fused @ w_f^T))
    {
        const int vg = tid >> 5;   // 0..7
        const int og = tid & 31;   // 0..31 -> outs og+32j, j=0..1
        float acc[4][2];
        #pragma unroll
        for (int i = 0; i < 4; ++i) { acc[i][0] = 0.f; acc[i][1] = 0.f; }
        const float4* wf4 = (const float4*)w_f;
        #pragma unroll 2
        for (int k4 = 0; k4 < 64; ++k4) {
            float4 fv[4];
            #pragma unroll
            for (int i = 0; i < 4; ++i)
                fv[i] = *(const float4*)&s_fused[(vg*4 + i)*260 + k4*4];
            float4 wv[2];
            #pragma unroll
            for (int j = 0; j < 2; ++j) wv[j] = wf4[(og + 32*j)*64 + k4];
            #pragma unroll
            for (int i = 0; i < 4; ++i)
                #pragma unroll
                for (int j = 0; j < 2; ++j) {
                    acc[i][j] = fmaf(fv[i].x, wv[j].x, acc[i][j]);
                    acc[i][j] = fmaf(fv[i].y, wv[j].y, acc[i][j]);
                    acc[i][j] = fmaf(fv[i].z, wv[j].z, acc[i][j]);
                    acc[i][j] = fmaf(fv[i].w, wv[j].w, acc[i][j]);
                }
        }
        #pragma unroll
        for (int j = 0; j < 2; ++j) {
            int o = og + 32*j;
            float a  = g_f[o] * rsqrtf(v_f[o] + EPSF);
            float bb = (b_f[o] - m_f[o]) * a + be_f[o];
            #pragma unroll
            for (int i = 0; i < 4; ++i)
                out[(v0 + vg*4 + i)*OUTC + o] = fmaxf(acc[i][j]*a + bb, 0.f);
        }
    }
}

// ---------------------------------------------------------------------------
extern "C" void kernel_launch(void* const* d_in, const int* in_sizes, int n_in,
                              void* d_out, int out_size, void* d_ws, size_t ws_size,
                              hipStream_t stream)
{
    const float* vf    = (const float*)d_in[0];
    const int*   vc    = (const int*)  d_in[1];
    const float* img   = (const float*)d_in[2];
    const float* gtb   = (const float*)d_in[3];
    const int*   gtc   = (const int*)  d_in[4];
    const float* w_vt  = (const float*)d_in[5];
    const float* b_vt  = (const float*)d_in[6];
    const float* g_vt  = (const float*)d_in[7];
    const float* be_vt = (const float*)d_in[8];
    const float* m_vt  = (const float*)d_in[9];
    const float* v_vt  = (const float*)d_in[10];
    const float* w_it  = (const float*)d_in[11];
    const float* b_it  = (const float*)d_in[12];
    const float* g_it  = (const float*)d_in[13];
    const float* be_it = (const float*)d_in[14];
    const float* m_it  = (const float*)d_in[15];
    const float* v_it  = (const float*)d_in[16];
    const float* w_f   = (const float*)d_in[17];
    const float* b_f   = (const float*)d_in[18];
    const float* g_f   = (const float*)d_in[19];
    const float* be_f  = (const float*)d_in[20];
    const float* m_f   = (const float*)d_in[21];
    const float* v_f   = (const float*)d_in[22];

    float* itbuf = (float*)d_ws;          // 4*29952*128*4 B = 61.3 MB
    float* outp  = (float*)d_out;

    img_transform<<<dim3(IHW/64, BATCH), 256, 0, stream>>>(
        img, w_it, b_it, g_it, be_it, m_it, v_it, itbuf);

    voxel_fuse<<<N_VOX/32, 256, 0, stream>>>(
        vf, vc, gtb, gtc, w_vt, b_vt, g_vt, be_vt, m_vt, v_vt,
        itbuf, w_f, b_f, g_f, be_f, m_f, v_f, outp);
}

// Round 2
// 150.986 us; speedup vs baseline: 6.0020x; 6.0020x over previous
//
#include <hip/hip_runtime.h>

typedef _Float16 half8  __attribute__((ext_vector_type(8)));
typedef _Float16 half4v __attribute__((ext_vector_type(4)));
typedef _Float16 half2v __attribute__((ext_vector_type(2)));
typedef float    f32x4  __attribute__((ext_vector_type(4)));

#define N_VOX  262144
#define BATCH  4
#define NBOX   32
#define C3D_   64
#define C2D_   256
#define MIDC   128
#define OUTC   64
#define IH     96
#define IW     312
#define IHW    (IH*IW)          // 29952
#define EPSF   1e-5f

#define MFMA16(a,b,c) __builtin_amdgcn_mfma_f32_16x16x32_f16(a,b,c,0,0,0)

// ---------------------------------------------------------------------------
// prep: fp32 weights -> fp16 copies in workspace
// ---------------------------------------------------------------------------
__global__ __launch_bounds__(256) void prep_weights(
    const float* __restrict__ w_vt, const float* __restrict__ w_f,
    const float* __restrict__ w_it,
    _Float16* __restrict__ w_vt_h, _Float16* __restrict__ w_f_h,
    _Float16* __restrict__ w_it_h)
{
    int t = blockIdx.x * 256 + threadIdx.x;
    if (t < MIDC*C3D_) w_vt_h[t] = (_Float16)w_vt[t];
    if (t < OUTC*C2D_) w_f_h[t]  = (_Float16)w_f[t];
    if (t < MIDC*C2D_) w_it_h[t] = (_Float16)w_it[t];
}

// ---------------------------------------------------------------------------
// Kernel A: it_h[b][p][o] = fp16(relu(BN(sum_c w_it[o][c]*img[b][c][p])))
// MFMA: M=64 pixels, N=128 outs, K=256 in 4 chunks of 64.
// ---------------------------------------------------------------------------
__global__ __launch_bounds__(256) void img_transform(
    const float* __restrict__ img,        // [B][256][H*W]
    const _Float16* __restrict__ w_it_h,  // [128][256] fp16
    const float* __restrict__ b_it, const float* __restrict__ g_it,
    const float* __restrict__ be_it, const float* __restrict__ m_it,
    const float* __restrict__ v_it,
    _Float16* __restrict__ it_h)          // [B][H*W][128] fp16
{
    __shared__ __align__(16) _Float16 s_x[64*72];   // [p][k-chunk], pitch 72

    const int p0   = blockIdx.x * 64;
    const int b    = blockIdx.y;
    const int tid  = threadIdx.x;
    const int lane = tid & 63;
    const int wv   = tid >> 6;
    const int r    = lane & 15;
    const int kh   = lane >> 4;

    // B fragments: wave wv owns outs [wv*32, wv*32+32)
    half8 bfA[2][8];
    #pragma unroll
    for (int nt = 0; nt < 2; ++nt)
        #pragma unroll
        for (int ks = 0; ks < 8; ++ks) {
            int o = wv*32 + nt*16 + r;
            bfA[nt][ks] = *(const half8*)&w_it_h[o*C2D_ + ks*32 + kh*8];
        }

    f32x4 acc[4][2] = {};

    const int p  = tid & 63;
    const int cb = (tid >> 6) * 2;

    for (int kc = 0; kc < 4; ++kc) {
        // stage 64 channels x 64 pixels, transposed -> [p][k] fp16
        #pragma unroll
        for (int i = 0; i < 8; ++i) {
            int c = cb + i*8;
            float x0 = img[(b*C2D_ + kc*64 + c    )*IHW + p0 + p];
            float x1 = img[(b*C2D_ + kc*64 + c + 1)*IHW + p0 + p];
            half2v h; h[0] = (_Float16)x0; h[1] = (_Float16)x1;
            *(half2v*)&s_x[p*72 + c] = h;
        }
        __syncthreads();
        #pragma unroll
        for (int mt = 0; mt < 4; ++mt)
            #pragma unroll
            for (int ks = 0; ks < 2; ++ks) {
                half8 af = *(const half8*)&s_x[(mt*16 + r)*72 + ks*32 + kh*8];
                acc[mt][0] = MFMA16(af, bfA[0][kc*2 + ks], acc[mt][0]);
                acc[mt][1] = MFMA16(af, bfA[1][kc*2 + ks], acc[mt][1]);
            }
        __syncthreads();
    }

    #pragma unroll
    for (int nt = 0; nt < 2; ++nt) {
        int o = wv*32 + nt*16 + r;
        float sa = g_it[o] * rsqrtf(v_it[o] + EPSF);
        float sb = (b_it[o] - m_it[o]) * sa + be_it[o];
        #pragma unroll
        for (int mt = 0; mt < 4; ++mt)
            #pragma unroll
            for (int rr = 0; rr < 4; ++rr) {
                int p2 = mt*16 + kh*4 + rr;
                float val = fmaxf(acc[mt][nt][rr]*sa + sb, 0.f);
                it_h[(size_t)(b*IHW + p0 + p2)*MIDC + o] = (_Float16)val;
            }
    }
}

// ---------------------------------------------------------------------------
// Kernel B: 64 voxels/block, 4 waves. meta -> vt MFMA -> fp16 gather ->
// final MFMA (K=256).
// ---------------------------------------------------------------------------
__global__ __launch_bounds__(256, 3) void voxel_fuse(
    const float* __restrict__ vf,     // [N][64]
    const int*   __restrict__ coords, // [N][4]
    const float* __restrict__ gtb,    // [B][32][7]
    const int*   __restrict__ gtc,    // [B][32]
    const _Float16* __restrict__ w_vt_h,  // [128][64]
    const float* __restrict__ b_vt, const float* __restrict__ g_vt,
    const float* __restrict__ be_vt, const float* __restrict__ m_vt,
    const float* __restrict__ v_vt,
    const _Float16* __restrict__ it_h,    // [B][H*W][128]
    const _Float16* __restrict__ w_f_h,   // [64][256]
    const float* __restrict__ b_f, const float* __restrict__ g_f,
    const float* __restrict__ be_f, const float* __restrict__ m_f,
    const float* __restrict__ v_f,
    float* __restrict__ out)          // [N][64]
{
    __shared__ __align__(16) _Float16 s_vf[64*72];      // [v][k], pitch 72
    __shared__ __align__(16) _Float16 s_fused[64*264];  // [v][ch], pitch 264
    __shared__ int   s_addr[4][64];
    __shared__ float s_wgt[4][64];
    __shared__ float s_w3d[64];

    const int tid  = threadIdx.x;
    const int lane = tid & 63;
    const int wv   = tid >> 6;
    const int v0   = blockIdx.x * 64;
    const int r    = lane & 15;
    const int kh   = lane >> 4;

    // stage voxel features -> fp16 [v][k]
    {
        int v = tid >> 2, kb = (tid & 3) * 16;
        const float4* src = (const float4*)(vf + (size_t)(v0 + v)*C3D_ + kb);
        #pragma unroll
        for (int i = 0; i < 4; ++i) {
            float4 x = src[i];
            half4v h;
            h[0] = (_Float16)x.x; h[1] = (_Float16)x.y;
            h[2] = (_Float16)x.z; h[3] = (_Float16)x.w;
            *(half4v*)&s_vf[v*72 + kb + i*4] = h;
        }
    }

    // weight fragments in registers
    half8 bvt[2][2];   // [nt][ks]  outs (2*wv+nt)*16+r
    #pragma unroll
    for (int nt = 0; nt < 2; ++nt)
        #pragma unroll
        for (int ks = 0; ks < 2; ++ks) {
            int o = (2*wv + nt)*16 + r;
            bvt[nt][ks] = *(const half8*)&w_vt_h[o*C3D_ + ks*32 + kh*8];
        }
    half8 bff[8];      // final gemm, outs wv*16+r
    #pragma unroll
    for (int ks = 0; ks < 8; ++ks) {
        int o = wv*16 + r;
        bff[ks] = *(const half8*)&w_f_h[o*C2D_ + ks*32 + kh*8];
    }

    // meta: corners / weights / w3d (same fp32 math as reference)
    if (tid < 64) {
        const int v = tid;
        const int4 cc = ((const int4*)coords)[v0 + v];
        const int b = cc.x;
        const float crx = cc.w * 0.05f + 0.0f;
        const float cry = cc.z * 0.05f - 40.0f;
        const float crz = cc.y * 0.1f  - 3.0f;
        const float px = (crx + 0.025f) * 10.f + 156.f;
        const float py = (cry + 0.025f) * 10.f + 48.f;
        const float nx = fminf(fmaxf(px / 312.f * 2.f - 1.f, -1.f), 1.f);
        const float ny = fminf(fmaxf(py / 96.f  * 2.f - 1.f, -1.f), 1.f);
        const float fx = ((nx + 1.f) * 312.f - 1.f) * 0.5f;
        const float fy = ((ny + 1.f) * 96.f  - 1.f) * 0.5f;
        const float x0f = floorf(fx), y0f = floorf(fy);
        const float wx1 = fx - x0f, wy1 = fy - y0f;
        const int x0 = (int)x0f, y0 = (int)y0f;
        #pragma unroll
        for (int c = 0; c < 4; ++c) {
            int xi = x0 + (c & 1), yi = y0 + (c >> 1);
            bool valid = (xi >= 0) && (xi < IW) && (yi >= 0) && (yi < IH);
            int xc = min(max(xi, 0), IW - 1);
            int yc = min(max(yi, 0), IH - 1);
            s_addr[c][v] = ((b*IH + yc)*IW + xc) * MIDC;
            float wx = (c & 1) ? wx1 : 1.f - wx1;
            float wy = (c >> 1) ? wy1 : 1.f - wy1;
            s_wgt[c][v] = valid ? wx * wy : 0.f;
        }
        const float* gb = gtb + b*NBOX*7;
        bool any = false; int last = 0;
        for (int m = 0; m < NBOX; ++m) {
            float dx = gb[m*7+3];
            bool in = (fabsf(crx - gb[m*7+0]) < dx * 0.5f) &&
                      (fabsf(cry - gb[m*7+1]) < gb[m*7+4] * 0.5f) &&
                      (fabsf(crz - gb[m*7+2]) < gb[m*7+5] * 0.5f) &&
                      (dx > 0.f);
            if (in) { any = true; last = m; }
        }
        float w3 = 0.8f;
        if (any) {
            int cls = gtc[b*NBOX + last];
            w3 = (cls == 0) ? 0.85f : ((cls == 1) ? 0.95f : 0.6f);
        }
        s_w3d[v] = w3;
    }
    __syncthreads();

    // phase 1a: vt = relu(BN(vf @ w_vt^T)) * w3d -> fused[v][0..127] (fp16)
    {
        float sa[2], sb[2];
        #pragma unroll
        for (int nt = 0; nt < 2; ++nt) {
            int o = (2*wv + nt)*16 + r;
            sa[nt] = g_vt[o] * rsqrtf(v_vt[o] + EPSF);
            sb[nt] = (b_vt[o] - m_vt[o]) * sa[nt] + be_vt[o];
        }
        #pragma unroll
        for (int mt = 0; mt < 4; ++mt) {
            f32x4 a0 = {0.f,0.f,0.f,0.f}, a1 = {0.f,0.f,0.f,0.f};
            #pragma unroll
            for (int ks = 0; ks < 2; ++ks) {
                half8 af = *(const half8*)&s_vf[(mt*16 + r)*72 + ks*32 + kh*8];
                a0 = MFMA16(af, bvt[0][ks], a0);
                a1 = MFMA16(af, bvt[1][ks], a1);
            }
            #pragma unroll
            for (int rr = 0; rr < 4; ++rr) {
                int v = mt*16 + kh*4 + rr;
                float w3 = s_w3d[v];
                s_fused[v*264 + (2*wv+0)*16 + r] =
                    (_Float16)(fmaxf(a0[rr]*sa[0] + sb[0], 0.f) * w3);
                s_fused[v*264 + (2*wv+1)*16 + r] =
                    (_Float16)(fmaxf(a1[rr]*sa[1] + sb[1], 0.f) * w3);
            }
        }
    }

    // phase 1b: bilinear gather (fp16 reads, fp32 math) -> fused[v][128..255]
    {
        int v = tid >> 2, ch0 = (tid & 3) * 32;
        float sc = 1.f - s_w3d[v];
        int a0 = s_addr[0][v], a1 = s_addr[1][v];
        int a2 = s_addr[2][v], a3 = s_addr[3][v];
        float g0 = s_wgt[0][v], g1 = s_wgt[1][v];
        float g2 = s_wgt[2][v], g3 = s_wgt[3][v];
        #pragma unroll
        for (int c8 = 0; c8 < 4; ++c8) {
            int ch = ch0 + c8*8;
            half8 h0 = *(const half8*)&it_h[a0 + ch];
            half8 h1 = *(const half8*)&it_h[a1 + ch];
            half8 h2 = *(const half8*)&it_h[a2 + ch];
            half8 h3 = *(const half8*)&it_h[a3 + ch];
            half8 res;
            #pragma unroll
            for (int i = 0; i < 8; ++i) {
                float s = g0*(float)h0[i] + g1*(float)h1[i]
                        + g2*(float)h2[i] + g3*(float)h3[i];
                res[i] = (_Float16)(s * sc);
            }
            *(half8*)&s_fused[v*264 + 128 + ch] = res;
        }
    }
    __syncthreads();

    // phase 2: out = relu(BN(fused @ w_f^T)), K=256
    {
        int o = wv*16 + r;
        float sa = g_f[o] * rsqrtf(v_f[o] + EPSF);
        float sb = (b_f[o] - m_f[o]) * sa + be_f[o];
        #pragma unroll
        for (int mt = 0; mt < 4; ++mt) {
            f32x4 acc = {0.f,0.f,0.f,0.f};
            #pragma unroll
            for (int ks = 0; ks < 8; ++ks) {
                half8 af = *(const half8*)&s_fused[(mt*16 + r)*264 + ks*32 + kh*8];
                acc = MFMA16(af, bff[ks], acc);
            }
            #pragma unroll
            for (int rr = 0; rr < 4; ++rr) {
                int v = v0 + mt*16 + kh*4 + rr;
                out[(size_t)v*OUTC + o] = fmaxf(acc[rr]*sa + sb, 0.f);
            }
        }
    }
}

// ---------------------------------------------------------------------------
extern "C" void kernel_launch(void* const* d_in, const int* in_sizes, int n_in,
                              void* d_out, int out_size, void* d_ws, size_t ws_size,
                              hipStream_t stream)
{
    const float* vf    = (const float*)d_in[0];
    const int*   vc    = (const int*)  d_in[1];
    const float* img   = (const float*)d_in[2];
    const float* gtb   = (const float*)d_in[3];
    const int*   gtc   = (const int*)  d_in[4];
    const float* w_vt  = (const float*)d_in[5];
    const float* b_vt  = (const float*)d_in[6];
    const float* g_vt  = (const float*)d_in[7];
    const float* be_vt = (const float*)d_in[8];
    const float* m_vt  = (const float*)d_in[9];
    const float* v_vt  = (const float*)d_in[10];
    const float* w_it  = (const float*)d_in[11];
    const float* b_it  = (const float*)d_in[12];
    const float* g_it  = (const float*)d_in[13];
    const float* be_it = (const float*)d_in[14];
    const float* m_it  = (const float*)d_in[15];
    const float* v_it  = (const float*)d_in[16];
    const float* w_f   = (const float*)d_in[17];
    const float* b_f   = (const float*)d_in[18];
    const float* g_f   = (const float*)d_in[19];
    const float* be_f  = (const float*)d_in[20];
    const float* m_f   = (const float*)d_in[21];
    const float* v_f   = (const float*)d_in[22];

    _Float16* ws_h   = (_Float16*)d_ws;
    _Float16* it_h   = ws_h;                               // 15,335,424 halves
    _Float16* w_vt_h = ws_h + (size_t)BATCH*IHW*MIDC;      // 8192
    _Float16* w_f_h  = w_vt_h + MIDC*C3D_;                 // 16384
    _Float16* w_it_h = w_f_h + OUTC*C2D_;                  // 32768
    float* outp = (float*)d_out;

    prep_weights<<<128, 256, 0, stream>>>(w_vt, w_f, w_it, w_vt_h, w_f_h, w_it_h);

    img_transform<<<dim3(IHW/64, BATCH), 256, 0, stream>>>(
        img, w_it_h, b_it, g_it, be_it, m_it, v_it, it_h);

    voxel_fuse<<<N_VOX/64, 256, 0, stream>>>(
        vf, vc, gtb, gtc, w_vt_h, b_vt, g_vt, be_vt, m_vt, v_vt,
        it_h, w_f_h, b_f, g_f, be_f, m_f, v_f, outp);
}

// Round 5
// 112.501 us; speedup vs baseline: 8.0553x; 1.3421x over previous
//
#include <hip/hip_runtime.h>

typedef _Float16 half8  __attribute__((ext_vector_type(8)));
typedef _Float16 half4v __attribute__((ext_vector_type(4)));
typedef _Float16 half2v __attribute__((ext_vector_type(2)));
typedef float    f32x4  __attribute__((ext_vector_type(4)));

#define N_VOX  262144
#define BATCH  4
#define NBOX   32
#define C3D_   64
#define C2D_   256
#define MIDC   128
#define OUTC   64
#define IH     96
#define IW     312
#define IHW    (IH*IW)          // 29952
#define EPSF   1e-5f

#define MFMA16(a,b,c) __builtin_amdgcn_mfma_f32_16x16x32_f16(a,b,c,0,0,0)

// ---------------------------------------------------------------------------
// prep: fp32 weights -> fp16 copies in workspace
// ---------------------------------------------------------------------------
__global__ __launch_bounds__(256) void prep_weights(
    const float* __restrict__ w_vt, const float* __restrict__ w_f,
    const float* __restrict__ w_it,
    _Float16* __restrict__ w_vt_h, _Float16* __restrict__ w_f_h,
    _Float16* __restrict__ w_it_h)
{
    int t = blockIdx.x * 256 + threadIdx.x;
    if (t < MIDC*C3D_) w_vt_h[t] = (_Float16)w_vt[t];
    if (t < OUTC*C2D_) w_f_h[t]  = (_Float16)w_f[t];
    if (t < MIDC*C2D_) w_it_h[t] = (_Float16)w_it[t];
}

// ---------------------------------------------------------------------------
// Kernel A: T = relu(BN(img @ w_it^T))  (64 px x 128 out per block),
// then J = T @ w_f[:,128:256]^T  -> J[b][p][64] fp16.
// Single LDS buffer reused: [p][72] during stage 1, [p][136] for T.
// ---------------------------------------------------------------------------
__global__ __launch_bounds__(256, 4) void img_transform(
    const float* __restrict__ img,        // [B][256][H*W]
    const _Float16* __restrict__ w_it_h,  // [128][256] fp16
    const _Float16* __restrict__ w_f_h,   // [64][256] fp16
    const float* __restrict__ b_it, const float* __restrict__ g_it,
    const float* __restrict__ be_it, const float* __restrict__ m_it,
    const float* __restrict__ v_it,
    _Float16* __restrict__ Jout)          // [B][H*W][64] fp16
{
    __shared__ __align__(16) _Float16 s_mem[64*136];

    const int p0   = blockIdx.x * 64;
    const int b    = blockIdx.y;
    const int tid  = threadIdx.x;
    const int lane = tid & 63;
    const int wv   = tid >> 6;
    const int r    = lane & 15;
    const int kh   = lane >> 4;

    f32x4 acc[4][2] = {};

    const int p  = tid & 63;
    const int cb = (tid >> 6) * 2;

    for (int kc = 0; kc < 4; ++kc) {
        // stage 64 channels x 64 pixels, transposed -> [p][k] fp16 (pitch 72)
        #pragma unroll
        for (int i = 0; i < 8; ++i) {
            int c = cb + i*8;
            float x0 = img[(size_t)(b*C2D_ + kc*64 + c    )*IHW + p0 + p];
            float x1 = img[(size_t)(b*C2D_ + kc*64 + c + 1)*IHW + p0 + p];
            half2v h; h[0] = (_Float16)x0; h[1] = (_Float16)x1;
            *(half2v*)&s_mem[p*72 + c] = h;
        }
        // B fragments for this k-chunk (L2-hot)
        half8 bw[2][2];
        #pragma unroll
        for (int nt = 0; nt < 2; ++nt)
            #pragma unroll
            for (int ks = 0; ks < 2; ++ks) {
                int o = wv*32 + nt*16 + r;
                bw[nt][ks] = *(const half8*)&w_it_h[o*C2D_ + kc*64 + ks*32 + kh*8];
            }
        __syncthreads();
        #pragma unroll
        for (int mt = 0; mt < 4; ++mt)
            #pragma unroll
            for (int ks = 0; ks < 2; ++ks) {
                half8 af = *(const half8*)&s_mem[(mt*16 + r)*72 + ks*32 + kh*8];
                acc[mt][0] = MFMA16(af, bw[0][ks], acc[mt][0]);
                acc[mt][1] = MFMA16(af, bw[1][ks], acc[mt][1]);
            }
        __syncthreads();
    }

    // BN + relu -> T into s_mem, now viewed as [p][136]
    #pragma unroll
    for (int nt = 0; nt < 2; ++nt) {
        int o = wv*32 + nt*16 + r;
        float sa = g_it[o] * rsqrtf(v_it[o] + EPSF);
        float sb = (b_it[o] - m_it[o]) * sa + be_it[o];
        #pragma unroll
        for (int mt = 0; mt < 4; ++mt)
            #pragma unroll
            for (int rr = 0; rr < 4; ++rr) {
                int p2 = mt*16 + kh*4 + rr;
                float val = fmaxf(acc[mt][nt][rr]*sa + sb, 0.f);
                s_mem[p2*136 + o] = (_Float16)val;
            }
    }
    __syncthreads();

    // stage 2: J = T @ w_f[:,128:]^T  (K=128)
    {
        const int o2 = wv*16 + r;
        half8 bf2[4];
        #pragma unroll
        for (int ks = 0; ks < 4; ++ks)
            bf2[ks] = *(const half8*)&w_f_h[o2*C2D_ + 128 + ks*32 + kh*8];
        #pragma unroll
        for (int mt = 0; mt < 4; ++mt) {
            f32x4 a2 = {0.f,0.f,0.f,0.f};
            #pragma unroll
            for (int ks = 0; ks < 4; ++ks) {
                half8 af = *(const half8*)&s_mem[(mt*16 + r)*136 + ks*32 + kh*8];
                a2 = MFMA16(af, bf2[ks], a2);
            }
            #pragma unroll
            for (int rr = 0; rr < 4; ++rr) {
                int p2 = mt*16 + kh*4 + rr;
                Jout[(size_t)(b*IHW + p0 + p2)*OUTC + o2] = (_Float16)a2[rr];
            }
        }
    }
}

// ---------------------------------------------------------------------------
// Kernel B: 64 voxels/block. Per-thread meta + early J-gather (register
// prefetch), vt MFMA (K=64), gather combine, final MFMA (K=128) + J add.
// ---------------------------------------------------------------------------
__global__ __launch_bounds__(256, 4) void voxel_fuse(
    const float* __restrict__ vf,     // [N][64]
    const int*   __restrict__ coords, // [N][4]
    const float* __restrict__ gtb,    // [B][32][7]
    const int*   __restrict__ gtc,    // [B][32]
    const _Float16* __restrict__ w_vt_h,  // [128][64]
    const float* __restrict__ b_vt, const float* __restrict__ g_vt,
    const float* __restrict__ be_vt, const float* __restrict__ m_vt,
    const float* __restrict__ v_vt,
    const _Float16* __restrict__ Jimg,    // [B][H*W][64]
    const _Float16* __restrict__ w_f_h,   // [64][256]
    const float* __restrict__ b_f, const float* __restrict__ g_f,
    const float* __restrict__ be_f, const float* __restrict__ m_f,
    const float* __restrict__ v_f,
    float* __restrict__ out)          // [N][64]
{
    __shared__ __align__(16) _Float16 s_vf[64*72];      // [v][k] pitch 72
    __shared__ __align__(16) _Float16 s_fused[64*136];  // [v][o] pitch 136
    __shared__ __align__(16) _Float16 s_j[64*72];       // [v][o] pitch 72
    __shared__ float s_w3d[64];

    const int tid  = threadIdx.x;
    const int lane = tid & 63;
    const int wv   = tid >> 6;
    const int v0   = blockIdx.x * 64;
    const int r    = lane & 15;
    const int kh   = lane >> 4;

    // ---- issue vf loads (fp32) ----
    const int vsv = tid >> 2, q_ = tid & 3;
    float4 vfr[4];
    {
        const float4* src = (const float4*)(vf + (size_t)(v0 + vsv)*C3D_ + q_*16);
        #pragma unroll
        for (int i = 0; i < 4; ++i) vfr[i] = src[i];
    }

    // ---- per-thread meta for own voxel (redundant x4, no LDS round-trip) ----
    const int4 cc = ((const int4*)coords)[v0 + vsv];
    const int vb = cc.x;
    const float crx = cc.w * 0.05f + 0.0f;
    const float cry = cc.z * 0.05f - 40.0f;
    const float crz = cc.y * 0.1f  - 3.0f;
    int ga[4]; float gw[4];
    {
        const float px = (crx + 0.025f) * 10.f + 156.f;
        const float py = (cry + 0.025f) * 10.f + 48.f;
        const float nx = fminf(fmaxf(px / 312.f * 2.f - 1.f, -1.f), 1.f);
        const float ny = fminf(fmaxf(py / 96.f  * 2.f - 1.f, -1.f), 1.f);
        const float fx = ((nx + 1.f) * 312.f - 1.f) * 0.5f;
        const float fy = ((ny + 1.f) * 96.f  - 1.f) * 0.5f;
        const float x0f = floorf(fx), y0f = floorf(fy);
        const float wx1 = fx - x0f, wy1 = fy - y0f;
        const int x0 = (int)x0f, y0 = (int)y0f;
        #pragma unroll
        for (int c = 0; c < 4; ++c) {
            int xi = x0 + (c & 1), yi = y0 + (c >> 1);
            bool valid = (xi >= 0) && (xi < IW) && (yi >= 0) && (yi < IH);
            int xc = min(max(xi, 0), IW - 1);
            int yc = min(max(yi, 0), IH - 1);
            ga[c] = ((vb*IH + yc)*IW + xc) * OUTC;
            float wx = (c & 1) ? wx1 : 1.f - wx1;
            float wy = (c >> 1) ? wy1 : 1.f - wy1;
            gw[c] = valid ? wx * wy : 0.f;
        }
    }

    // ---- issue J-gather loads early (consumed after phase 1a) ----
    half8 jreg[4][2];
    #pragma unroll
    for (int c = 0; c < 4; ++c)
        #pragma unroll
        for (int h = 0; h < 2; ++h)
            jreg[c][h] = *(const half8*)&Jimg[ga[c] + (h*4 + q_)*8];

    // ---- stage vf -> fp16 LDS ----
    #pragma unroll
    for (int i = 0; i < 4; ++i) {
        float4 x = vfr[i];
        half4v h;
        h[0] = (_Float16)x.x; h[1] = (_Float16)x.y;
        h[2] = (_Float16)x.z; h[3] = (_Float16)x.w;
        *(half4v*)&s_vf[vsv*72 + q_*16 + i*4] = h;
    }

    // ---- weight fragments in registers ----
    half8 bvt[2][2];
    #pragma unroll
    for (int nt = 0; nt < 2; ++nt)
        #pragma unroll
        for (int ks = 0; ks < 2; ++ks) {
            int o = (2*wv + nt)*16 + r;
            bvt[nt][ks] = *(const half8*)&w_vt_h[o*C3D_ + ks*32 + kh*8];
        }
    const int of = wv*16 + r;
    half8 bf1[4];
    #pragma unroll
    for (int ks = 0; ks < 4; ++ks)
        bf1[ks] = *(const half8*)&w_f_h[of*C2D_ + ks*32 + kh*8];

    // ---- box membership: thread with q_==0 owns voxel vsv (meta is correct
    //      for vsv, NOT for tid — this was the round-3 bug) ----
    if (q_ == 0) {
        const float* gb = gtb + vb*NBOX*7;
        bool any = false; int last = 0;
        for (int m = 0; m < NBOX; ++m) {
            float dx = gb[m*7+3];
            bool in = (fabsf(crx - gb[m*7+0]) < dx * 0.5f) &&
                      (fabsf(cry - gb[m*7+1]) < gb[m*7+4] * 0.5f) &&
                      (fabsf(crz - gb[m*7+2]) < gb[m*7+5] * 0.5f) &&
                      (dx > 0.f);
            if (in) { any = true; last = m; }
        }
        float w3 = 0.8f;
        if (any) {
            int cls = gtc[vb*NBOX + last];
            w3 = (cls == 0) ? 0.85f : ((cls == 1) ? 0.95f : 0.6f);
        }
        s_w3d[vsv] = w3;
    }
    __syncthreads();

    // ---- phase 1a: vt = relu(BN(vf @ w_vt^T)) * w3d -> s_fused ----
    {
        float sa[2], sb[2];
        #pragma unroll
        for (int nt = 0; nt < 2; ++nt) {
            int o = (2*wv + nt)*16 + r;
            sa[nt] = g_vt[o] * rsqrtf(v_vt[o] + EPSF);
            sb[nt] = (b_vt[o] - m_vt[o]) * sa[nt] + be_vt[o];
        }
        #pragma unroll
        for (int mt = 0; mt < 4; ++mt) {
            f32x4 a0 = {0.f,0.f,0.f,0.f}, a1 = {0.f,0.f,0.f,0.f};
            #pragma unroll
            for (int ks = 0; ks < 2; ++ks) {
                half8 af = *(const half8*)&s_vf[(mt*16 + r)*72 + ks*32 + kh*8];
                a0 = MFMA16(af, bvt[0][ks], a0);
                a1 = MFMA16(af, bvt[1][ks], a1);
            }
            #pragma unroll
            for (int rr = 0; rr < 4; ++rr) {
                int v = mt*16 + kh*4 + rr;
                float w3 = s_w3d[v];
                s_fused[v*136 + (2*wv+0)*16 + r] =
                    (_Float16)(fmaxf(a0[rr]*sa[0] + sb[0], 0.f) * w3);
                s_fused[v*136 + (2*wv+1)*16 + r] =
                    (_Float16)(fmaxf(a1[rr]*sa[1] + sb[1], 0.f) * w3);
            }
        }
    }

    // ---- gather combine: (1-w3d) * sum_c gw[c]*J_c -> s_j ----
    {
        float invw = 1.f - s_w3d[vsv];
        #pragma unroll
        for (int h = 0; h < 2; ++h) {
            half8 res;
            #pragma unroll
            for (int i = 0; i < 8; ++i) {
                float s = gw[0]*(float)jreg[0][h][i] + gw[1]*(float)jreg[1][h][i]
                        + gw[2]*(float)jreg[2][h][i] + gw[3]*(float)jreg[3][h][i];
                res[i] = (_Float16)(s * invw);
            }
            *(half8*)&s_j[vsv*72 + (h*4 + q_)*8] = res;
        }
    }
    __syncthreads();

    // ---- phase 2: out = relu(BN(vt_part @ Wf1^T + j)) , K=128 ----
    {
        float sa = g_f[of] * rsqrtf(v_f[of] + EPSF);
        float sb = (b_f[of] - m_f[of]) * sa + be_f[of];
        #pragma unroll
        for (int mt = 0; mt < 4; ++mt) {
            f32x4 acc = {0.f,0.f,0.f,0.f};
            #pragma unroll
            for (int ks = 0; ks < 4; ++ks) {
                half8 af = *(const half8*)&s_fused[(mt*16 + r)*136 + ks*32 + kh*8];
                acc = MFMA16(af, bf1[ks], acc);
            }
            #pragma unroll
            for (int rr = 0; rr < 4; ++rr) {
                int v = mt*16 + kh*4 + rr;
                float jv = (float)s_j[v*72 + of];
                out[(size_t)(v0 + v)*OUTC + of] =
                    fmaxf((acc[rr] + jv)*sa + sb, 0.f);
            }
        }
    }
}

// ---------------------------------------------------------------------------
extern "C" void kernel_launch(void* const* d_in, const int* in_sizes, int n_in,
                              void* d_out, int out_size, void* d_ws, size_t ws_size,
                              hipStream_t stream)
{
    const float* vf    = (const float*)d_in[0];
    const int*   vc    = (const int*)  d_in[1];
    const float* img   = (const float*)d_in[2];
    const float* gtb   = (const float*)d_in[3];
    const int*   gtc   = (const int*)  d_in[4];
    const float* w_vt  = (const float*)d_in[5];
    const float* b_vt  = (const float*)d_in[6];
    const float* g_vt  = (const float*)d_in[7];
    const float* be_vt = (const float*)d_in[8];
    const float* m_vt  = (const float*)d_in[9];
    const float* v_vt  = (const float*)d_in[10];
    const float* w_it  = (const float*)d_in[11];
    const float* b_it  = (const float*)d_in[12];
    const float* g_it  = (const float*)d_in[13];
    const float* be_it = (const float*)d_in[14];
    const float* m_it  = (const float*)d_in[15];
    const float* v_it  = (const float*)d_in[16];
    const float* w_f   = (const float*)d_in[17];
    const float* b_f   = (const float*)d_in[18];
    const float* g_f   = (const float*)d_in[19];
    const float* be_f  = (const float*)d_in[20];
    const float* m_f   = (const float*)d_in[21];
    const float* v_f   = (const float*)d_in[22];

    _Float16* ws_h   = (_Float16*)d_ws;
    _Float16* Jbuf   = ws_h;                              // B*IHW*64 halves
    _Float16* w_vt_h = ws_h + (size_t)BATCH*IHW*OUTC;
    _Float16* w_f_h  = w_vt_h + MIDC*C3D_;
    _Float16* w_it_h = w_f_h + OUTC*C2D_;
    float* outp = (float*)d_out;

    prep_weights<<<128, 256, 0, stream>>>(w_vt, w_f, w_it, w_vt_h, w_f_h, w_it_h);

    img_transform<<<dim3(IHW/64, BATCH), 256, 0, stream>>>(
        img, w_it_h, w_f_h, b_it, g_it, be_it, m_it, v_it, Jbuf);

    voxel_fuse<<<N_VOX/64, 256, 0, stream>>>(
        vf, vc, gtb, gtc, w_vt_h, b_vt, g_vt, be_vt, m_vt, v_vt,
        Jbuf, w_f_h, b_f, g_f, be_f, m_f, v_f, outp);
}